// Round 1
// baseline (23442.973 us; speedup 1.0000x reference)
//
#include <hip/hip_runtime.h>
#include <math.h>

namespace {
constexpr int cS = 64, cI = 128, cNO = 64, cK = 64, cD = 64, cB = 64, cT = 256;
constexpr float cTH = 0.01f;

__device__ inline float wave_reduce_max64(float v) {
    #pragma unroll
    for (int m = 1; m < 64; m <<= 1) v = fmaxf(v, __shfl_xor(v, m));
    return v;
}
__device__ inline float wave_reduce_sum64(float v) {
    #pragma unroll
    for (int m = 1; m < 64; m <<= 1) v += __shfl_xor(v, m);
    return v;
}

__global__ __launch_bounds__(512, 1)
void fpt_kernel(const int* __restrict__ seq,
                const float* __restrict__ Tm,     // (S,I,D,S)
                const float* __restrict__ Om,     // (S,I,D,NO)
                const float* __restrict__ pgate,  // (S,I,1)
                const float* __restrict__ qgate,  // (S,I,1)
                const float* __restrict__ pval,   // (S,I,D)
                const float* __restrict__ initl,  // (S,)
                float* __restrict__ out)          // (B,T,NO)
{
    const int b = blockIdx.x;
    const int tid = threadIdx.x;
    const int wave = tid >> 6;
    const int lane = tid & 63;

    __shared__ float s_state[cS];
    __shared__ float s_nstate[cS];
    __shared__ float s_stack[cD];
    __shared__ float s_pushv[cD];
    __shared__ float s_ptr[cK];
    __shared__ float s_ptr2[cK];
    __shared__ float s_w[cK];
    __shared__ float s_content[cK][cD];
    __shared__ float s_redA[8][64];
    __shared__ float s_redB[8][64];
    __shared__ float s_opart[4][cNO];
    __shared__ float s_npart[4][cS];
    __shared__ float s_push, s_pop;

    // ---- init carry ----
    if (wave == 0) {
        float v = initl[lane];
        float m = wave_reduce_max64(v);
        float e = expf(v - m);
        float s = wave_reduce_sum64(e);
        s_state[lane] = e / s;
    } else if (wave == 1) {
        s_ptr[lane] = (lane == 0) ? 1.0f : 0.0f;
    }
    for (int idx = tid; idx < cK * cD; idx += 512)
        (&s_content[0][0])[idx] = 0.0f;
    __syncthreads();

    const int dq = lane >> 4;   // 0..3 : which 16-wide d-chunk
    const int o4 = lane & 15;   // 0..15: which float4 of the 64 outputs

    for (int t = 0; t < cT; ++t) {
        const int inp = seq[b * cT + t];

        // ---- Phase A1: partials for stack_top (ptr@content) and push_v (state@pval) ----
        {
            float accA = 0.f, accB = 0.f;
            #pragma unroll
            for (int j = 0; j < 8; ++j) {
                int k = wave * 8 + j;
                accA += s_ptr[k] * s_content[k][lane];
                accB += s_state[k] * pval[(k * cI + inp) * cD + lane];
            }
            s_redA[wave][lane] = accA;
            s_redB[wave][lane] = accB;
        }
        __syncthreads();

        // ---- Phase A2: finalize stack_top, push_v, gates ----
        if (wave == 0) {
            float a = 0.f;
            #pragma unroll
            for (int g = 0; g < 8; ++g) a += s_redA[g][lane];
            s_stack[lane] = a;
        } else if (wave == 1) {
            float a = 0.f;
            #pragma unroll
            for (int g = 0; g < 8; ++g) a += s_redB[g][lane];
            s_pushv[lane] = tanhf(a);
        } else if (wave == 2) {
            float v = pgate[lane * cI + inp] * s_state[lane];
            float d = wave_reduce_sum64(v);
            if (lane == 0) s_push = 1.0f / (1.0f + expf(-d));
        } else if (wave == 3) {
            float v = qgate[lane * cI + inp] * s_state[lane];
            float d = wave_reduce_sum64(v);
            if (lane == 0) s_pop = 1.0f / (1.0f + expf(-d));
        }
        __syncthreads();

        // ---- Phase B: 64 O-rows on waves 0..3, 64 T-rows on waves 4..7 ----
        {
            const bool isO = (wave < 4);
            const int w4 = isO ? wave : (wave - 4);
            const float* Mbase = isO ? Om : Tm;

            float xs[16];
            #pragma unroll
            for (int i = 0; i < 16; ++i) xs[i] = s_stack[dq * 16 + i];

            float4 oacc = make_float4(0.f, 0.f, 0.f, 0.f);
            for (int r = 0; r < 16; ++r) {
                const int s = w4 * 16 + r;
                const float4* rowp =
                    reinterpret_cast<const float4*>(Mbase + (size_t)(s * cI + inp) * (cD * 64)) + o4;
                float4 acc = make_float4(0.f, 0.f, 0.f, 0.f);
                #pragma unroll
                for (int i = 0; i < 16; ++i) {
                    float4 mv = rowp[(dq * 16 + i) * 16];
                    float xd = xs[i];
                    acc.x = fmaf(xd, mv.x, acc.x);
                    acc.y = fmaf(xd, mv.y, acc.y);
                    acc.z = fmaf(xd, mv.z, acc.z);
                    acc.w = fmaf(xd, mv.w, acc.w);
                }
                // reduce the 4 d-chunks (lanes differing in bits 4,5)
                #pragma unroll
                for (int m = 16; m < 64; m <<= 1) {
                    acc.x += __shfl_xor(acc.x, m);
                    acc.y += __shfl_xor(acc.y, m);
                    acc.z += __shfl_xor(acc.z, m);
                    acc.w += __shfl_xor(acc.w, m);
                }
                // softmax over the 64 row values (4 per lane across 16 o4 lanes)
                float mx = fmaxf(fmaxf(acc.x, acc.y), fmaxf(acc.z, acc.w));
                #pragma unroll
                for (int m = 1; m < 16; m <<= 1) mx = fmaxf(mx, __shfl_xor(mx, m));
                float4 e;
                e.x = expf(acc.x - mx); e.y = expf(acc.y - mx);
                e.z = expf(acc.z - mx); e.w = expf(acc.w - mx);
                float sm = e.x + e.y + e.z + e.w;
                #pragma unroll
                for (int m = 1; m < 16; m <<= 1) sm += __shfl_xor(sm, m);
                float coef = s_state[s] / sm;
                oacc.x = fmaf(coef, e.x, oacc.x);
                oacc.y = fmaf(coef, e.y, oacc.y);
                oacc.z = fmaf(coef, e.z, oacc.z);
                oacc.w = fmaf(coef, e.w, oacc.w);
            }
            if (dq == 0) {
                float* dst = isO ? &s_opart[w4][0] : &s_npart[w4][0];
                dst[o4 * 4 + 0] = oacc.x;
                dst[o4 * 4 + 1] = oacc.y;
                dst[o4 * 4 + 2] = oacc.z;
                dst[o4 * 4 + 3] = oacc.w;
            }
        }
        __syncthreads();

        // ---- Phase C1: write output, reduce new_state, apply pop to pointer ----
        if (wave == 0) {
            float o = s_opart[0][lane] + s_opart[1][lane] + s_opart[2][lane] + s_opart[3][lane];
            out[((size_t)b * cT + t) * cNO + lane] = o;
        } else if (wave == 1) {
            s_nstate[lane] = s_npart[0][lane] + s_npart[1][lane] + s_npart[2][lane] + s_npart[3][lane];
        } else if (wave == 2) {
            float p = s_ptr[lane];
            float sd = (lane < cK - 1) ? s_ptr[lane + 1] : 0.f;
            float pop = s_pop;
            float pp = pop * sd + (1.f - pop) * p;
            s_ptr2[lane] = (pop > cTH) ? pp : p;
        }
        __syncthreads();

        // ---- Phase C2: push pointer + w; commit new state ----
        if (wave == 0) {
            float p2 = s_ptr2[lane];
            float su = (lane > 0) ? s_ptr2[lane - 1] : 0.f;
            float push = s_push;
            float pp = push * su + (1.f - push) * p2;
            s_w[lane] = pp;
            s_ptr[lane] = (push > cTH) ? pp : p2;
        } else if (wave == 1) {
            s_state[lane] = s_nstate[lane];
        }
        __syncthreads();

        // ---- Phase C3: content update (uniform branch) ----
        if (s_push > cTH) {
            for (int idx = tid; idx < cK * cD; idx += 512) {
                int k = idx >> 6, d = idx & 63;
                float w = s_w[k];
                s_content[k][d] = s_content[k][d] * (1.f - w) + s_pushv[d] * w;
            }
        }
        __syncthreads();
    }
}
} // namespace

extern "C" void kernel_launch(void* const* d_in, const int* in_sizes, int n_in,
                              void* d_out, int out_size, void* d_ws, size_t ws_size,
                              hipStream_t stream) {
    const int*   seq = (const int*)d_in[0];
    const float* Tm  = (const float*)d_in[1];
    const float* Om  = (const float*)d_in[2];
    const float* pg  = (const float*)d_in[3];
    const float* qg  = (const float*)d_in[4];
    const float* pv  = (const float*)d_in[5];
    const float* il  = (const float*)d_in[6];
    float* o   = (float*)d_out;
    hipLaunchKernelGGL(fpt_kernel, dim3(cB), dim3(512), 0, stream,
                       seq, Tm, Om, pg, qg, pv, il, o);
}